// Round 1
// 130.658 us; speedup vs baseline: 1.2305x; 1.2305x over previous
//
#include <hip/hip_runtime.h>

// MHSA: B=2, S=2048, D=1024, H=16, HD=64.  All matmuls bf16 MFMA, fp32 accum.

typedef __bf16 bf16x8 __attribute__((ext_vector_type(8)));
typedef float f32x4 __attribute__((ext_vector_type(4)));
typedef float f32x16 __attribute__((ext_vector_type(16)));

#define AS1 __attribute__((address_space(1)))
#define AS3 __attribute__((address_space(3)))

__device__ __forceinline__ ushort f2bf(float f) {
  unsigned u = __builtin_bit_cast(unsigned, f);
  u += 0x7fffu + ((u >> 16) & 1u);
  return (ushort)(u >> 16);
}

__device__ __forceinline__ unsigned cvt_pk_bf16(float lo, float hi) {
  unsigned r;
  asm("v_cvt_pk_bf16_f32 %0, %1, %2" : "=v"(r) : "v"(lo), "v"(hi));
  return r;  // lo -> [15:0], hi -> [31:16]
}

__device__ __forceinline__ bf16x8 ld16(const ushort* p) {
  return __builtin_bit_cast(bf16x8, *(const uint4*)p);
}

__device__ __forceinline__ void gload16(const ushort* g, ushort* l) {
  __builtin_amdgcn_global_load_lds((const AS1 void*)g, (AS3 void*)l, 16, 0, 0);
}

#define MFMA32(a, b, c) __builtin_amdgcn_mfma_f32_32x32x16_bf16(a, b, c, 0, 0, 0)

// ---------------- cast f32 -> bf16 (vectorized) ----------------
__global__ void cast_bf16(const float4* __restrict__ in, ushort4* __restrict__ out, int n4) {
  int stride = gridDim.x * blockDim.x;
  for (int i = blockIdx.x * blockDim.x + threadIdx.x; i < n4; i += stride) {
    float4 v = in[i];
    ushort4 r;
    r.x = f2bf(v.x); r.y = f2bf(v.y); r.z = f2bf(v.z); r.w = f2bf(v.w);
    out[i] = r;
  }
}

// 4 weight matrices (each 1024x1024 f32) -> one contiguous bf16 buffer.
__global__ void cast4_bf16(const float4* __restrict__ a, const float4* __restrict__ b,
                           const float4* __restrict__ c, const float4* __restrict__ d,
                           ushort4* __restrict__ out) {
  const int n4each = 262144;  // 2^18
  int stride = gridDim.x * blockDim.x;
  for (int i = blockIdx.x * blockDim.x + threadIdx.x; i < 4 * n4each; i += stride) {
    int seg = i >> 18, off = i & (n4each - 1);
    const float4* s = seg == 0 ? a : seg == 1 ? b : seg == 2 ? c : d;
    float4 v = s[off];
    ushort4 r;
    r.x = f2bf(v.x); r.y = f2bf(v.y); r.z = f2bf(v.z); r.w = f2bf(v.w);
    out[i] = r;
  }
}

// ---------------- NT GEMM: C[m][n] = sum_k A[m][k]*B[n][k] ----------------
// 128x128 tile, BK=64, 4 waves (2x2), 16x16x32 bf16 MFMA, XOR-swizzled LDS.
template <bool F32OUT>
__global__ __launch_bounds__(256) void gemm_nt(const ushort* __restrict__ A,
                                               const ushort* __restrict__ B,
                                               void* __restrict__ Cv,
                                               int M, int N, int K) {
  __shared__ ushort As[128 * 64];
  __shared__ ushort Bs[128 * 64];
  const int tid = threadIdx.x;
  const int lane = tid & 63;
  const int wave = tid >> 6;
  const int r15 = lane & 15, hi = lane >> 4;
  const int bm = blockIdx.y * 128, bn = blockIdx.x * 128;
  const int wm = (wave >> 1) * 64, wn = (wave & 1) * 64;

  f32x4 acc[4][4] = {};

  const int KT = K >> 6;
  for (int kt = 0; kt < KT; ++kt) {
#pragma unroll
    for (int i = 0; i < 4; ++i) {
      int c = i * 256 + tid;          // 1024 chunks of 16B per matrix
      int row = c >> 3, slot = c & 7;
      int coff = kt * 64 + ((((slot * 16) ^ ((row & 7) << 4))) >> 1);  // ushort offset
      gload16(A + (size_t)(bm + row) * K + coff, As + c * 8);
      gload16(B + (size_t)(bn + row) * K + coff, Bs + c * 8);
    }
    __syncthreads();
#pragma unroll
    for (int kc = 0; kc < 2; ++kc) {
      bf16x8 af[4], bfr[4];
#pragma unroll
      for (int mi = 0; mi < 4; ++mi) {
        int ra = wm + mi * 16 + r15;
        af[mi] = ld16(As + ra * 64 + ((kc * 32 + hi * 8) ^ ((ra & 7) << 3)));
      }
#pragma unroll
      for (int nj = 0; nj < 4; ++nj) {
        int rb = wn + nj * 16 + r15;
        bfr[nj] = ld16(Bs + rb * 64 + ((kc * 32 + hi * 8) ^ ((rb & 7) << 3)));
      }
#pragma unroll
      for (int mi = 0; mi < 4; ++mi)
#pragma unroll
        for (int nj = 0; nj < 4; ++nj)
          acc[mi][nj] = __builtin_amdgcn_mfma_f32_16x16x32_bf16(af[mi], bfr[nj], acc[mi][nj], 0, 0, 0);
    }
    __syncthreads();
  }

#pragma unroll
  for (int mi = 0; mi < 4; ++mi)
#pragma unroll
    for (int nj = 0; nj < 4; ++nj) {
      int row = bm + wm + mi * 16 + hi * 4;
      int col = bn + wn + nj * 16 + r15;
#pragma unroll
      for (int j = 0; j < 4; ++j) {
        if (F32OUT)
          ((float*)Cv)[(size_t)(row + j) * N + col] = acc[mi][nj][j];
        else
          ((ushort*)Cv)[(size_t)(row + j) * N + col] = f2bf(acc[mi][nj][j]);
      }
    }
}

// ---------------- causal flash attention (swapped 32x32 MFMA, pipelined) ----
// QKV fused [B,S,3072]: Q at col 0, K at +1024, V at +2048.
// grid = (16, B*H=32); block = 512 = 8 waves.
// In-block KV-split: waves 0-3 (kh=0) do kv tiles [0,nh), waves 4-7 (kh=1)
// do [nh,2nh) over the SAME 128 q rows; pair (w, w+4) merges (m,l,O) via LDS.
// Each half has its own double-buffered K/V LDS; next tile's K
// (global_load_lds) + V (reg) loads issued BEFORE compute, V written late.
// qt remap: co-resident block pair (id, id+256) gets complementary qt so
// per-CU work is ~constant (17 half-tiles).
__global__ __launch_bounds__(512, 4) void attn_fwd(const ushort* __restrict__ QKV,
                                                   ushort* __restrict__ Om) {
  __shared__ ushort Ks[2][2][4096];   // [kv-half][buf][64 kv x 64 d swz]
  __shared__ ushort Vs[2][2][4096];

  const int tid = threadIdx.x, lane = tid & 63, wave = tid >> 6;
  const int l31 = lane & 31, hi = lane >> 5;
  const int kh = wave >> 2;          // kv half: 0 = lower, 1 = upper
  const int hw = wave & 3;           // q sub-tile within half
  const int htid = tid & 255;        // thread id within half
  const int qt = (blockIdx.y < 16) ? (15 - (int)blockIdx.x) : (int)blockIdx.x;
  const int bh = blockIdx.y;
  const size_t base = (size_t)(bh >> 4) * (2048 * 3072) + (bh & 15) * 64;
  const size_t obase = (size_t)(bh >> 4) * (2048 * 1024) + (bh & 15) * 64;
  const int qbase = qt * 128 + hw * 32;
  const int qrow = qbase + l31;      // this lane's q row (softmax owner)
  const int nh = qt + 1;             // kv tiles per half

  // Q fragments: Q[qrow][c*16 + hi*8 + 0..7], c = 0..3
  bf16x8 qf[4];
  {
    const ushort* qp = QKV + base + (size_t)qrow * 3072 + hi * 8;
#pragma unroll
    for (int c = 0; c < 4; ++c) qf[c] = ld16(qp + c * 16);
  }

  // per-lane staging addresses (K: 2 chunks; V: 2 dwordx4), per half
  const int c0row = htid >> 3, c0slot = htid & 7;
  const int c1row = 32 + (htid >> 3), c1slot = htid & 7;
  const ushort* kg0 = QKV + base + 1024 + (size_t)c0row * 3072 +
                      ((((c0slot * 16) ^ ((c0row & 7) << 4))) >> 1);
  const ushort* kg1 = QKV + base + 1024 + (size_t)c1row * 3072 +
                      ((((c1slot * 16) ^ ((c1row & 7) << 4))) >> 1);
  const ushort* vg = QKV + base + 2048 + (size_t)lane * 3072 + hw * 8;

  f32x16 o0 = {}, o1 = {};           // O^T acc: col=q=l31, row=d (o1: d+32)
  float m_r = -3e38f, l_r = 0.f;
  const float Cc = 0.125f * 1.44269504f;   // 1/sqrt(64) * log2(e)

  // ---- prologue: stage tile kh*nh into buf 0 of this half's LDS ----
  {
    const size_t t0off = (size_t)(kh * nh) * (64 * 3072);
    gload16(kg0 + t0off, &Ks[kh][0][htid * 8]);
    gload16(kg1 + t0off, &Ks[kh][0][(256 + htid) * 8]);
#pragma unroll
    for (int i = 0; i < 2; ++i) {
      int d0 = hw * 8 + i * 32;
      union { uint4 u; ushort s[8]; } uv;
      uv.u = *(const uint4*)(vg + t0off + i * 32);
#pragma unroll
      for (int j = 0; j < 8; ++j) {
        int d = d0 + j;
        Vs[kh][0][d * 64 + (lane ^ ((d & 7) << 3))] = uv.s[j];
      }
    }
  }
  __syncthreads();

  for (int t = 0; t < nh; ++t) {
    const int tile = kh * nh + t;
    const int buf = t & 1;
    const bool pre = (t + 1 < nh);
    uint4 va0, va1;
    // ---- issue next tile's loads (hidden under this tile's compute) ----
    if (pre) {
      const size_t roff = (size_t)(tile + 1) * (64 * 3072);
      gload16(kg0 + roff, &Ks[kh][buf ^ 1][htid * 8]);
      gload16(kg1 + roff, &Ks[kh][buf ^ 1][(256 + htid) * 8]);
      va0 = *(const uint4*)(vg + roff);
      va1 = *(const uint4*)(vg + roff + 32);
    }

    const int kvb = tile * 64;
    if (kvb <= qbase + 31) {   // wave-uniform: at least one unmasked (q,kv)
      // ---- S^T = K Q^T : two kv-half accs ----
      f32x16 s0 = {}, s1 = {};
#pragma unroll
      for (int c = 0; c < 4; ++c) {
        int col = c * 16 + hi * 8;
        int r0 = l31, r1 = 32 + l31;
        bf16x8 k0 = ld16(&Ks[kh][buf][r0 * 64 + (col ^ ((r0 & 7) << 3))]);
        bf16x8 k1 = ld16(&Ks[kh][buf][r1 * 64 + (col ^ ((r1 & 7) << 3))]);
        s0 = MFMA32(k0, qf[c], s0);
        s1 = MFMA32(k1, qf[c], s1);
      }

      // ---- causal mask (wave-uniform branch) ----
      if (kvb + 63 > qbase) {
#pragma unroll
        for (int r = 0; r < 16; ++r) {
          int kvl = (r & 3) + 8 * (r >> 2) + 4 * hi;
          if (kvb + kvl > qrow) s0[r] = -3e38f;
          if (kvb + 32 + kvl > qrow) s1[r] = -3e38f;
        }
      }

      // ---- online softmax: lane pair (l, l^32) owns one q row ----
      // tree max (depth ~5 instead of 32-deep chain)
      float tm[8];
#pragma unroll
      for (int r = 0; r < 8; ++r)
        tm[r] = fmaxf(fmaxf(s0[r], s1[r]), fmaxf(s0[r + 8], s1[r + 8]));
#pragma unroll
      for (int off = 4; off > 0; off >>= 1)
#pragma unroll
        for (int r = 0; r < off; ++r) tm[r] = fmaxf(tm[r], tm[r + off]);
      float mx = fmaxf(tm[0], __shfl_xor(tm[0], 32));

      float mnew = fmaxf(m_r, mx);
      bool up = mnew > m_r;
      float sc = exp2f((m_r - mnew) * Cc);
      m_r = mnew;
      float mC = mnew * Cc;
      float p0[16], p1[16];
#pragma unroll
      for (int r = 0; r < 16; ++r) {
        p0[r] = exp2f(fmaf(s0[r], Cc, -mC));
        p1[r] = exp2f(fmaf(s1[r], Cc, -mC));
      }
      // tree sum
      float ts[8];
#pragma unroll
      for (int r = 0; r < 8; ++r)
        ts[r] = (p0[r] + p1[r]) + (p0[r + 8] + p1[r + 8]);
#pragma unroll
      for (int off = 4; off > 0; off >>= 1)
#pragma unroll
        for (int r = 0; r < off; ++r) ts[r] += ts[r + off];
      float rs = ts[0] + __shfl_xor(ts[0], 32);

      if (__any(up)) {           // defer-rescale: skip x1.0 passes
        l_r *= sc;
#pragma unroll
        for (int r = 0; r < 16; ++r) { o0[r] *= sc; o1[r] *= sc; }
      }
      l_r += rs;

      // ---- P -> bf16 B-fragments (cvt_pk + in-register exchange) + PV ----
#pragma unroll
      for (int c = 0; c < 4; ++c) {
        const float* ph = (c >> 1) ? p1 : p0;
        const int o = (c & 1) * 8;
        unsigned uA0 = cvt_pk_bf16(ph[o + 0], ph[o + 1]);
        unsigned uA1 = cvt_pk_bf16(ph[o + 2], ph[o + 3]);
        unsigned uB0 = cvt_pk_bf16(ph[o + 4], ph[o + 5]);
        unsigned uB1 = cvt_pk_bf16(ph[o + 6], ph[o + 7]);
        unsigned r0 = __shfl_xor(hi ? uA0 : uB0, 32);
        unsigned r1 = __shfl_xor(hi ? uA1 : uB1, 32);
        uint4 y;
        y.x = hi ? r0 : uA0;
        y.y = hi ? r1 : uA1;
        y.z = hi ? uB0 : r0;
        y.w = hi ? uB1 : r1;
        bf16x8 pf = __builtin_bit_cast(bf16x8, y);

        int col = c * 16 + hi * 8;
        int d0r = l31, d1r = 32 + l31;
        bf16x8 v0 = ld16(&Vs[kh][buf][d0r * 64 + (col ^ ((d0r & 7) << 3))]);
        bf16x8 v1 = ld16(&Vs[kh][buf][d1r * 64 + (col ^ ((d1r & 7) << 3))]);
        o0 = MFMA32(v0, pf, o0);
        o1 = MFMA32(v1, pf, o1);
      }
    }

    // ---- late V write for next tile (vmcnt wait covered by compute) ----
    if (pre) {
#pragma unroll
      for (int i = 0; i < 2; ++i) {
        int d0 = hw * 8 + i * 32;
        union { uint4 u; ushort s[8]; } uv;
        uv.u = i ? va1 : va0;
#pragma unroll
        for (int j = 0; j < 8; ++j) {
          int d = d0 + j;
          Vs[kh][buf ^ 1][d * 64 + (lane ^ ((d & 7) << 3))] = uv.s[j];
        }
      }
    }
    __syncthreads();
  }

  // ---- kv-split combine: pair (wave hw, wave hw+4) merge via LDS ----
  float* osh = (float*)&Vs[0][0][0];              // 32 KiB: [4 hw][32 r][64 lane]
  float* mlsh = (float*)(&Ks[0][0][0] + 8192);    // 1 KiB, after sm region
  ushort* sm = &Ks[0][0][0];                      // 16 KiB = [128 q][64 d] bf16
  if (kh) {
#pragma unroll
    for (int r = 0; r < 16; ++r) {
      osh[(hw * 32 + r) * 64 + lane] = o0[r];
      osh[(hw * 32 + 16 + r) * 64 + lane] = o1[r];
    }
    if (lane < 32) {
      mlsh[hw * 32 + lane] = m_r;
      mlsh[128 + hw * 32 + lane] = l_r;
    }
  }
  __syncthreads();
  if (!kh) {
    float m_hi = mlsh[hw * 32 + l31];
    float l_hi = mlsh[128 + hw * 32 + l31];
    float M = fmaxf(m_r, m_hi);
    float ea = exp2f((m_r - M) * Cc);     // ==1 unless upper half dominates
    float eb = exp2f((m_hi - M) * Cc);    // ==0 for fully-masked upper half
    float linv = 1.0f / (l_r * ea + l_hi * eb);
    float fa = ea * linv, fb = eb * linv;
    int q = hw * 32 + l31;
#pragma unroll
    for (int r = 0; r < 16; ++r) {
      float v0 = fmaf(o0[r], fa, osh[(hw * 32 + r) * 64 + lane] * fb);
      float v1 = fmaf(o1[r], fa, osh[(hw * 32 + 16 + r) * 64 + lane] * fb);
      int d = (r & 3) + 8 * (r >> 2) + 4 * hi;
      sm[q * 64 + (d ^ ((q & 7) << 3))] = f2bf(v0);
      int d2 = d + 32;
      sm[q * 64 + (d2 ^ ((q & 7) << 3))] = f2bf(v1);
    }
  }
  __syncthreads();
  // ---- coalesced store: 2 iters x 512 threads over [128][64] ----
#pragma unroll
  for (int i = 0; i < 2; ++i) {
    int c2 = i * 512 + tid;
    int row = c2 >> 3, slot = c2 & 7;
    uint4 v = *(const uint4*)(sm + row * 64 + ((slot * 8) ^ ((row & 7) << 3)));
    *(uint4*)(Om + obase + (size_t)(qt * 128 + row) * 1024 + slot * 8) = v;
  }
}

// ---------------- launcher ----------------
extern "C" void kernel_launch(void* const* d_in, const int* in_sizes, int n_in,
                              void* d_out, int out_size, void* d_ws, size_t ws_size,
                              hipStream_t stream) {
  (void)in_sizes; (void)n_in; (void)out_size; (void)ws_size;
  const float* x = (const float*)d_in[0];
  const float* qw = (const float*)d_in[1];
  const float* kw = (const float*)d_in[2];
  const float* vw = (const float*)d_in[3];
  const float* ow = (const float*)d_in[4];
  float* out = (float*)d_out;

  const int NT = 4096;   // B*S tokens
  const int D = 1024;

  ushort* xb   = (ushort*)d_ws;                // [4096][1024]
  ushort* wqkv = xb + (size_t)NT * D;          // [3072][1024] (q,k,v rows)
  ushort* wob  = wqkv + (size_t)3 * D * D;     // [1024][1024]
  ushort* QKVb = wob + (size_t)D * D;          // [4096][3072]
  ushort* Ob   = QKVb + (size_t)NT * 3 * D;    // [4096][1024]

  // casts (q,k,v,o weights contiguous: wqkv then wob)
  cast_bf16<<<2048, 256, 0, stream>>>((const float4*)x, (ushort4*)xb, NT * D / 4);
  cast4_bf16<<<1024, 256, 0, stream>>>((const float4*)qw, (const float4*)kw,
                                       (const float4*)vw, (const float4*)ow,
                                       (ushort4*)wqkv);

  // fused QKV projection: [4096,1024] x [3072,1024]^T -> [4096,3072]
  gemm_nt<false><<<dim3(3 * D / 128, NT / 128), 256, 0, stream>>>(xb, wqkv, QKVb, NT, 3 * D, D);

  // causal flash attention (8-wave blocks, in-block kv-split)
  attn_fwd<<<dim3(16, 32), 512, 0, stream>>>(QKVb, Ob);

  // output projection (f32 out)
  gemm_nt<true><<<dim3(D / 128, NT / 128), 256, 0, stream>>>(Ob, wob, out, NT, D, D);
}